// Round 4
// baseline (93.522 us; speedup 1.0000x reference)
//
#include <hip/hip_runtime.h>

// GraphAdjacencyLayer: W[i][j] = thresh((fn_i . fn_j)^2), fn = row-normalized features.
// N x 128 fp32 in, N x N fp32 out (N=8192). Output 256 MB is the write roofline (~39 us
// at the 6.9 TB/s the harness fill kernel demonstrates).
//
// K1: fn = f32_normalize(row); bf16 fn -> d_ws (2 MB, L2-resident).
// K2: 64x256 output tile per 256-thread block. bf16 MFMA (swapped operands), threshold
//     in-register, stage the tile in XOR-swizzled LDS (64 KB), then stream out with
//     FULL-ROW stores: each wave store-inst writes 1 KB contiguous (64 lanes x 16 B)
//     -> all full 128B L2 lines, half the write-request count of the scattered layout.
//     XCD-aware block swizzle clusters each XCD's writes into a contiguous 32 MB region.

typedef __bf16 bf16x8 __attribute__((ext_vector_type(8)));
typedef float f32x4 __attribute__((ext_vector_type(4)));

// ---------------- K1: row-normalize fp32 -> bf16 ----------------------------
__global__ __launch_bounds__(256)
void norm_cvt_kernel(const float* __restrict__ F, unsigned short* __restrict__ Fb, int N)
{
    const int gtid = blockIdx.x * 256 + threadIdx.x;
    const int row  = gtid >> 5;
    const int c    = gtid & 31;          // float4 column
    if (row >= N) return;

    float4 v = ((const float4*)F)[(size_t)row * 32 + c];
    float ss = v.x * v.x + v.y * v.y + v.z * v.z + v.w * v.w;
    #pragma unroll
    for (int m = 1; m <= 16; m <<= 1) ss += __shfl_xor(ss, m, 64);   // within 32-group
    const float s = 1.0f / (sqrtf(ss) + 1e-12f);

    ushort4 u;
    u.x = __builtin_bit_cast(unsigned short, (__bf16)(v.x * s));
    u.y = __builtin_bit_cast(unsigned short, (__bf16)(v.y * s));
    u.z = __builtin_bit_cast(unsigned short, (__bf16)(v.z * s));
    u.w = __builtin_bit_cast(unsigned short, (__bf16)(v.w * s));
    ((ushort4*)Fb)[(size_t)row * 32 + c] = u;
}

// ---------------- K2: Gram + threshold + LDS-transpose epilogue --------------
// Block tile: 64 rows x 256 cols. Wave w computes rows 0..63 x cols [w*64, w*64+64).
// Swapped mfma(b,a): lane (fr=lane&15, fkq=lane>>4) holds output row fr, cols fkq*4+reg.
__global__ __launch_bounds__(256, 2)
void gram_thresh_kernel(const unsigned short* __restrict__ Fb, float* __restrict__ out, int N)
{
    __shared__ __align__(16) float TILE[64 * 256];   // 64 KB, XOR-swizzled

    const int tid  = threadIdx.x;
    const int lane = tid & 63;
    const int w    = tid >> 6;           // wave 0..3 -> col quadrant
    const int fr   = lane & 15;          // output-row within fragment
    const int fkq  = lane >> 4;          // output-col quad 0..3

    // flat grid 4096 = 128 row-bands (64 rows) x 32 col-strips (256 cols), XCD-swizzled
    const int bid  = blockIdx.x;
    const int nwg  = gridDim.x;
    const int lbid = (bid & 7) * (nwg >> 3) + (bid >> 3);
    const int band  = lbid >> 5;         // 0..127
    const int strip = lbid & 31;         // 0..31
    const int r0 = band * 64;
    const int c0 = strip * 256;

    const bf16x8* __restrict__ base = (const bf16x8*)Fb;   // row stride = 16 chunks
    const int rowA0 = r0 + fr;                    // + m*16
    const int rowB0 = c0 + w * 64 + fr;           // + n*16

    // preload B fragments for this wave's 64 columns
    bf16x8 b[4][4];
    #pragma unroll
    for (int n = 0; n < 4; ++n)
        #pragma unroll
        for (int ks = 0; ks < 4; ++ks)
            b[n][ks] = base[(size_t)(rowB0 + n * 16) * 16 + ks * 4 + fkq];

    const float c1 = 0.9486832980505138f;  // sqrt(0.9)
    const float c2 = 0.7071067811865476f;  // sqrt(0.5)
    const bool diagBlock = (band >> 2) == strip;

    #pragma unroll
    for (int m = 0; m < 4; ++m) {
        bf16x8 a[4];
        #pragma unroll
        for (int ks = 0; ks < 4; ++ks)
            a[ks] = base[(size_t)(rowA0 + m * 16) * 16 + ks * 4 + fkq];

        f32x4 acc[4];
        #pragma unroll
        for (int n = 0; n < 4; ++n) acc[n] = (f32x4){0.f, 0.f, 0.f, 0.f};

        #pragma unroll
        for (int ks = 0; ks < 4; ++ks)
            #pragma unroll
            for (int n = 0; n < 4; ++n)
                acc[n] = __builtin_amdgcn_mfma_f32_16x16x32_bf16(b[n][ks], a[ks], acc[n], 0, 0, 0);

        const int rloc = m * 16 + fr;             // tile-local output row
        const int grow = r0 + rloc;               // global row

        #pragma unroll
        for (int n = 0; n < 4; ++n) {
            const int cloc = w * 64 + n * 16 + fkq * 4;   // tile-local col
            f32x4 wv;
            #pragma unroll
            for (int j = 0; j < 4; ++j) {
                const float g = fabsf(acc[n][j]);
                wv[j] = g >= c1 ? 1.0f : (g >= c2 ? 0.5f : 0.0f);
            }
            if (diagBlock) {
                const int d = grow - (c0 + cloc);
                if (d >= 0 && d < 4) wv[d] = 0.0f;   // reversed index: col - row... see note
            }
            // note: diagonal element is (grow, gcol) with gcol = c0+cloc+j -> j = grow-(c0+cloc)
            const unsigned byte = (unsigned)rloc * 1024u + (unsigned)cloc * 4u;
            const unsigned swz  = byte ^ ((unsigned)(rloc & 7) << 4);
            *(f32x4*)((char*)TILE + swz) = wv;
        }
    }

    __syncthreads();

    // stream out: wave w, pass p -> tile row p*4+w; 64 lanes cover the full 1 KB row
    #pragma unroll
    for (int p = 0; p < 16; ++p) {
        const int rloc = p * 4 + w;
        const unsigned byte = (unsigned)rloc * 1024u + (unsigned)lane * 16u;
        const unsigned swz  = byte ^ ((unsigned)(rloc & 7) << 4);
        const f32x4 v = *(const f32x4*)((const char*)TILE + swz);
        *(f32x4*)(out + (size_t)(r0 + rloc) * N + c0 + lane * 4) = v;
    }
}

extern "C" void kernel_launch(void* const* d_in, const int* in_sizes, int n_in,
                              void* d_out, int out_size, void* d_ws, size_t ws_size,
                              hipStream_t stream) {
    const float* features = (const float*)d_in[0];
    float* out = (float*)d_out;
    const int D = 128;
    const int N = in_sizes[0] / D;   // 8192

    unsigned short* Fb = (unsigned short*)d_ws;
    const int k1_blocks = (N * 32 + 255) / 256;
    norm_cvt_kernel<<<k1_blocks, 256, 0, stream>>>(features, Fb, N);

    const int nblk = (N / 64) * (N / 256);   // 4096
    gram_thresh_kernel<<<nblk, 256, 0, stream>>>(Fb, out, N);
}

// Round 5
// 83.855 us; speedup vs baseline: 1.1153x; 1.1153x over previous
//
#include <hip/hip_runtime.h>

// GraphAdjacencyLayer: W[i][j] = thresh((fn_i . fn_j)^2), fn = row-normalized features.
// N x 128 fp32 in, N x N fp32 out (N=8192). Output 256 MB is the write roofline (~39 us
// at the 6.9 TB/s the harness fill kernel demonstrates).
//
// R5 theory: L2 write-allocate (RFO) doubles HBM traffic on output stores
// (74 us * 6.9 TB/s == 512 MB == 2x output). Fix: NONTEMPORAL float4 stores
// (nt flag -> no L2 allocate, no line fill). Structure otherwise identical to the
// best-so-far R3 kernel (swapped-operand MFMA, no LDS, float4 stores).

typedef __bf16 bf16x8 __attribute__((ext_vector_type(8)));
typedef float f32x4 __attribute__((ext_vector_type(4)));

// ---------------- K1: row-normalize fp32 -> bf16 ----------------------------
__global__ __launch_bounds__(256)
void norm_cvt_kernel(const float* __restrict__ F, unsigned short* __restrict__ Fb, int N)
{
    const int gtid = blockIdx.x * 256 + threadIdx.x;
    const int row  = gtid >> 5;
    const int c    = gtid & 31;          // float4 column
    if (row >= N) return;

    float4 v = ((const float4*)F)[(size_t)row * 32 + c];
    float ss = v.x * v.x + v.y * v.y + v.z * v.z + v.w * v.w;
    #pragma unroll
    for (int m = 1; m <= 16; m <<= 1) ss += __shfl_xor(ss, m, 64);   // within 32-group
    const float s = 1.0f / (sqrtf(ss) + 1e-12f);

    ushort4 u;
    u.x = __builtin_bit_cast(unsigned short, (__bf16)(v.x * s));
    u.y = __builtin_bit_cast(unsigned short, (__bf16)(v.y * s));
    u.z = __builtin_bit_cast(unsigned short, (__bf16)(v.z * s));
    u.w = __builtin_bit_cast(unsigned short, (__bf16)(v.w * s));
    ((ushort4*)Fb)[(size_t)row * 32 + c] = u;
}

// ---------------- K2: Gram + threshold, nontemporal float4 stores ------------
// 128x128 tile per 256-thread block (4 waves, 2x2 of 64x64). K=128, no K-loop.
// acc[n] = mfma(b[n], a): lane (fr=lane&15, fkq=lane>>4) holds output row fr,
// cols fkq*4 + 0..3 (consecutive) -> one float4 of W per fragment per lane.
__global__ __launch_bounds__(256, 3)
void gram_thresh_kernel(const unsigned short* __restrict__ Fb, float* __restrict__ out, int N)
{
    const int tid  = threadIdx.x;
    const int lane = tid & 63;
    const int wid  = tid >> 6;
    const int wm   = wid >> 1;
    const int wn   = wid & 1;
    const int fr   = lane & 15;          // fragment row index
    const int fkq  = lane >> 4;          // col quad 0..3

    const int rowTile = blockIdx.y * 128;
    const int colTile = blockIdx.x * 128;

    const bf16x8* __restrict__ base = (const bf16x8*)Fb;   // row stride = 16 chunks
    const int rowA0 = rowTile + wm * 64 + fr;
    const int rowB0 = colTile + wn * 64 + fr;

    // preload all B fragments (output-column rows): 16 loads, 64 VGPR
    bf16x8 b[4][4];
    #pragma unroll
    for (int n = 0; n < 4; ++n)
        #pragma unroll
        for (int ks = 0; ks < 4; ++ks)
            b[n][ks] = base[(size_t)(rowB0 + n * 16) * 16 + ks * 4 + fkq];

    const float c1 = 0.9486832980505138f;  // sqrt(0.9)
    const float c2 = 0.7071067811865476f;  // sqrt(0.5)
    const bool diagBlock = (rowTile == colTile);

    #pragma unroll
    for (int m = 0; m < 4; ++m) {
        bf16x8 a[4];
        #pragma unroll
        for (int ks = 0; ks < 4; ++ks)
            a[ks] = base[(size_t)(rowA0 + m * 16) * 16 + ks * 4 + fkq];

        f32x4 acc[4];
        #pragma unroll
        for (int n = 0; n < 4; ++n) acc[n] = (f32x4){0.f, 0.f, 0.f, 0.f};

        #pragma unroll
        for (int ks = 0; ks < 4; ++ks)
            #pragma unroll
            for (int n = 0; n < 4; ++n)
                acc[n] = __builtin_amdgcn_mfma_f32_16x16x32_bf16(b[n][ks], a[ks], acc[n], 0, 0, 0);

        const int grow = rowTile + wm * 64 + m * 16 + fr;
        float* __restrict__ orow = out + (size_t)grow * N;

        #pragma unroll
        for (int n = 0; n < 4; ++n) {
            const int c0 = colTile + wn * 64 + n * 16 + fkq * 4;
            f32x4 wv;
            #pragma unroll
            for (int j = 0; j < 4; ++j) {
                const float g = fabsf(acc[n][j]);
                wv[j] = g >= c1 ? 1.0f : (g >= c2 ? 0.5f : 0.0f);
            }
            if (diagBlock) {
                const int d = grow - c0;        // component hit if 0..3
                if (d >= 0 && d < 4) wv[d] = 0.0f;
            }
            __builtin_nontemporal_store(wv, (f32x4*)(orow + c0));
        }
    }
}

extern "C" void kernel_launch(void* const* d_in, const int* in_sizes, int n_in,
                              void* d_out, int out_size, void* d_ws, size_t ws_size,
                              hipStream_t stream) {
    const float* features = (const float*)d_in[0];
    float* out = (float*)d_out;
    const int D = 128;
    const int N = in_sizes[0] / D;   // 8192

    unsigned short* Fb = (unsigned short*)d_ws;
    const int k1_blocks = (N * 32 + 255) / 256;
    norm_cvt_kernel<<<k1_blocks, 256, 0, stream>>>(features, Fb, N);

    dim3 grid(N / 128, N / 128);
    gram_thresh_kernel<<<grid, dim3(256), 0, stream>>>(Fb, out, N);
}

// Round 6
// 79.760 us; speedup vs baseline: 1.1725x; 1.0513x over previous
//
#include <hip/hip_runtime.h>

// GraphAdjacencyLayer: W[i][j] = thresh((fn_i . fn_j)^2), fn = row-normalized features.
// N x 128 fp32 in, N x N fp32 out (N=8192). 256 MB output; write roofline ~39 us
// (rocclr fill demonstrates 6.9 TB/s on this chip).
//
// R6: decouple output bytes from compute. Each wave STREAMS ZEROS over its own
// 64x64 output quadrant (no data dependency -> stores issue from cycle 0, like the
// fill kernel), while MFMA computes the Gram tile on the matrix pipe. Non-zeros
// (fid >= 0.5; provably absent for this input but handled for correctness) are
// detected via __any() and scatter-written in a branch that skips when empty.
// Same-wave ownership of zero-region and scatter-region + vmcnt(0) in the branch
// gives store ordering without any __syncthreads.

typedef __bf16 bf16x8 __attribute__((ext_vector_type(8)));
typedef float f32x4 __attribute__((ext_vector_type(4)));

// ---------------- K1: row-normalize fp32 -> bf16 ----------------------------
__global__ __launch_bounds__(256)
void norm_cvt_kernel(const float* __restrict__ F, unsigned short* __restrict__ Fb, int N)
{
    const int gtid = blockIdx.x * 256 + threadIdx.x;
    const int row  = gtid >> 5;
    const int c    = gtid & 31;          // float4 column
    if (row >= N) return;

    float4 v = ((const float4*)F)[(size_t)row * 32 + c];
    float ss = v.x * v.x + v.y * v.y + v.z * v.z + v.w * v.w;
    #pragma unroll
    for (int m = 1; m <= 16; m <<= 1) ss += __shfl_xor(ss, m, 64);   // within 32-group
    const float s = 1.0f / (sqrtf(ss) + 1e-12f);

    ushort4 u;
    u.x = __builtin_bit_cast(unsigned short, (__bf16)(v.x * s));
    u.y = __builtin_bit_cast(unsigned short, (__bf16)(v.y * s));
    u.z = __builtin_bit_cast(unsigned short, (__bf16)(v.z * s));
    u.w = __builtin_bit_cast(unsigned short, (__bf16)(v.w * s));
    ((ushort4*)Fb)[(size_t)row * 32 + c] = u;
}

// ---------------- K2: zero-stream + Gram + rare scatter ----------------------
// 128x128 tile per 256-thread block (4 waves, 2x2 of 64x64 quadrants).
// Swapped mfma(b,a): lane (fr=lane&15, fkq=lane>>4) holds output row fr,
// cols fkq*4+0..3 within each 16x16 fragment.
__global__ __launch_bounds__(256, 3)
void gram_zero_scatter(const unsigned short* __restrict__ Fb, float* __restrict__ out, int N)
{
    const int tid  = threadIdx.x;
    const int lane = tid & 63;
    const int wid  = tid >> 6;
    const int wm   = wid >> 1;
    const int wn   = wid & 1;
    const int fr   = lane & 15;
    const int fkq  = lane >> 4;

    const int rowTile = blockIdx.y * 128;
    const int colTile = blockIdx.x * 128;
    const int qr = rowTile + wm * 64;     // this wave's quadrant rows
    const int qc = colTile + wn * 64;     // this wave's quadrant cols

    // -------- phase 0: stream zeros over own 64x64 quadrant (no dependencies) ----
    // per inst: 4 rows x (16 lanes x 16 B) = 4 x 256 B; 16 insts cover 64 rows.
    {
        const int zr = lane >> 4;              // 0..3
        const int zc = (lane & 15) << 2;       // float offset 0..60
        float* zp = out + (size_t)(qr + zr) * N + (qc + zc);
        const f32x4 z = {0.f, 0.f, 0.f, 0.f};
        #pragma unroll
        for (int p = 0; p < 16; ++p)
            *(f32x4*)(zp + (size_t)p * 4 * N) = z;
    }

    // -------- Gram tile (bf16 MFMA, swapped operands) -----------------------------
    const bf16x8* __restrict__ base = (const bf16x8*)Fb;   // row stride = 16 chunks
    const int rowA0 = qr + fr;
    const int rowB0 = qc + fr;

    bf16x8 b[4][4];
    #pragma unroll
    for (int n = 0; n < 4; ++n)
        #pragma unroll
        for (int ks = 0; ks < 4; ++ks)
            b[n][ks] = base[(size_t)(rowB0 + n * 16) * 16 + ks * 4 + fkq];

    const float c1 = 0.9486832980505138f;  // sqrt(0.9)
    const float c2 = 0.7071067811865476f;  // sqrt(0.5)

    #pragma unroll
    for (int m = 0; m < 4; ++m) {
        bf16x8 a[4];
        #pragma unroll
        for (int ks = 0; ks < 4; ++ks)
            a[ks] = base[(size_t)(rowA0 + m * 16) * 16 + ks * 4 + fkq];

        f32x4 acc[4];
        #pragma unroll
        for (int n = 0; n < 4; ++n) acc[n] = (f32x4){0.f, 0.f, 0.f, 0.f};

        #pragma unroll
        for (int ks = 0; ks < 4; ++ks)
            #pragma unroll
            for (int n = 0; n < 4; ++n)
                acc[n] = __builtin_amdgcn_mfma_f32_16x16x32_bf16(b[n][ks], a[ks], acc[n], 0, 0, 0);

        const int grow = qr + m * 16 + fr;

        // -------- rare-hit detection + scatter (skipped via execz when empty) ----
        #pragma unroll
        for (int n = 0; n < 4; ++n) {
            const int c0 = qc + n * 16 + fkq * 4;
            const float g0 = fabsf(acc[n][0]);
            const float g1 = fabsf(acc[n][1]);
            const float g2 = fabsf(acc[n][2]);
            const float g3 = fabsf(acc[n][3]);
            const float mx = fmaxf(fmaxf(g0, g1), fmaxf(g2, g3));
            if (__any(mx >= c2)) {
                // ensure this wave's zero-stores to this quadrant have landed
                asm volatile("s_waitcnt vmcnt(0)" ::: "memory");
                #pragma unroll
                for (int j = 0; j < 4; ++j) {
                    const float g = fabsf(acc[n][j]);
                    const int gcol = c0 + j;
                    if (g >= c2 && grow != gcol)
                        out[(size_t)grow * N + gcol] = (g >= c1) ? 1.0f : 0.5f;
                }
            }
        }
    }
}

extern "C" void kernel_launch(void* const* d_in, const int* in_sizes, int n_in,
                              void* d_out, int out_size, void* d_ws, size_t ws_size,
                              hipStream_t stream) {
    const float* features = (const float*)d_in[0];
    float* out = (float*)d_out;
    const int D = 128;
    const int N = in_sizes[0] / D;   // 8192

    unsigned short* Fb = (unsigned short*)d_ws;
    const int k1_blocks = (N * 32 + 255) / 256;
    norm_cvt_kernel<<<k1_blocks, 256, 0, stream>>>(features, Fb, N);

    dim3 grid(N / 128, N / 128);
    gram_zero_scatter<<<grid, dim3(256), 0, stream>>>(Fb, out, N);
}